// Round 5
// baseline (495.927 us; speedup 1.0000x reference)
//
#include <hip/hip_runtime.h>
#include <hip/hip_bf16.h>

typedef __hip_bfloat16 bf16;
typedef unsigned short u16;
typedef __attribute__((ext_vector_type(4))) short short4_t;
typedef __attribute__((ext_vector_type(8))) short short8;
typedef __attribute__((ext_vector_type(4))) float f32x4;

#define LEAK 0.1f
#define EPS_ 1e-5f
#define MFMA(a, b, c) __builtin_amdgcn_mfma_f32_16x16x32_bf16(a, b, c, 0, 0, 0)
// N=32 C=64 T=400 V=27 S=2 IC=16 O=64 -- fp32 I/O, bf16 MFMA internally

__device__ __forceinline__ float u2f(u16 u) { return __uint_as_float(((unsigned int)u) << 16); }
__device__ __forceinline__ u16 f2u(float f) {
  bf16 h = __float2bfloat16(f);
  u16 r;
  __builtin_memcpy(&r, &h, 2);
  return r;
}
__device__ __forceinline__ f32x4 z4() { f32x4 z = {0.f, 0.f, 0.f, 0.f}; return z; }
__device__ __forceinline__ short8 z8() { short8 z = {0, 0, 0, 0, 0, 0, 0, 0}; return z; }
// 8-byte-aligned 16-byte LDS load (for stride-76 rows)
__device__ __forceinline__ short8 ld8_8al(const u16* p) {
  short4_t a = *(const short4_t*)p;
  short4_t b = *(const short4_t*)(p + 4);
  short8 r;
#pragma unroll
  for (int j = 0; j < 4; ++j) { r[j] = a[j]; r[4 + j] = b[j]; }
  return r;
}

// ---------------------------------------------------------------------------
// K1: attention logits. Block = (n, 8 contiguous t). Coalesced staging of
// (x+pe)^T, ONE barrier, then wave-private qk-GEMM + logit MFMAs (wave owns
// slices {w, w+4}), logits accumulate in registers; block-reduce, 1 atomic/cell.
// ---------------------------------------------------------------------------
__global__ __launch_bounds__(256) void k_att(
    const float* __restrict__ x, const float* __restrict__ pe,
    const float* __restrict__ W_in, const float* __restrict__ b_in,
    float* __restrict__ att_raw)
{
  __shared__ u16 syT[221][76];       // (x+pe)^T: row = sl*27+v, col = c (stride 76: 2-way banks)
  __shared__ u16 sqkT[4][32][72];    // per-wave qk^T [v][r]
  __shared__ float sb[64];
  const int tid = threadIdx.x, w = tid >> 6, lane = tid & 63;
  const int m = lane & 15, quad = lane >> 4;
  const int n = blockIdx.y, t0 = blockIdx.x * 8;
  const long xb = (long)n * 691200 + t0 * 27;

  short8 aWin[4][2];  // A = W_in rows 16mt+m, cols 32kf+8quad+j
#pragma unroll
  for (int mt = 0; mt < 4; ++mt)
#pragma unroll
    for (int kf = 0; kf < 2; ++kf) {
      short8 tt;
#pragma unroll
      for (int j = 0; j < 8; ++j)
        tt[j] = (short)f2u(W_in[(16 * mt + m) * 64 + 32 * kf + 8 * quad + j]);
      aWin[mt][kf] = tt;
    }
  if (tid < 64) sb[tid] = b_in[tid];

  f32x4 acc[2][2][2];  // [s][u-tile][v-tile] logits, accumulated over slices
#pragma unroll
  for (int s = 0; s < 2; ++s)
#pragma unroll
    for (int a = 0; a < 2; ++a)
#pragma unroll
      for (int b = 0; b < 2; ++b) acc[s][a][b] = z4();

  // coalesced staging: per c, 216 contiguous floats (8 slices x 27 v)
  for (int i = tid; i < 64 * 216; i += 256) {
    int c = i / 216, f = i % 216;
    syT[f][c] = f2u(x[xb + (long)c * 10800 + f] + pe[c * 10800 + t0 * 27 + f]);
  }
  __syncthreads();

#pragma unroll
  for (int ss = 0; ss < 2; ++ss) {
    const int sl = w + 4 * ss, rb = sl * 27;
    // qk GEMM: D[r][v], full M per wave
    f32x4 q[4][2];
#pragma unroll
    for (int mt = 0; mt < 4; ++mt)
#pragma unroll
      for (int nt = 0; nt < 2; ++nt) q[mt][nt] = z4();
#pragma unroll
    for (int kf = 0; kf < 2; ++kf)
#pragma unroll
      for (int nt = 0; nt < 2; ++nt) {
        short8 b = ld8_8al(&syT[rb + 16 * nt + m][32 * kf + 8 * quad]);
#pragma unroll
        for (int mt = 0; mt < 4; ++mt) q[mt][nt] = MFMA(aWin[mt][kf], b, q[mt][nt]);
      }
#pragma unroll
    for (int mt = 0; mt < 4; ++mt)
#pragma unroll
      for (int nt = 0; nt < 2; ++nt) {
        int v = 16 * nt + m;
        if (v < 27) {
          short4_t pk;
#pragma unroll
          for (int reg = 0; reg < 4; ++reg)
            pk[reg] = (short)f2u(q[mt][nt][reg] + sb[16 * mt + 4 * quad + reg]);
          *(short4_t*)&sqkT[w][v][16 * mt + 4 * quad] = pk;
        }
      }
    __asm__ volatile("s_waitcnt lgkmcnt(0)" ::: "memory");
    // logits: per s, A = q^T (K=16 real, quads>=2 zero), B = k
#pragma unroll
    for (int s = 0; s < 2; ++s) {
      short8 aq[2], bk[2];
#pragma unroll
      for (int ua = 0; ua < 2; ++ua)
        aq[ua] = (quad < 2) ? *(const short8*)&sqkT[w][16 * ua + m][16 * s + 8 * quad] : z8();
#pragma unroll
      for (int nt = 0; nt < 2; ++nt)
        bk[nt] = (quad < 2) ? *(const short8*)&sqkT[w][16 * nt + m][32 + 16 * s + 8 * quad] : z8();
#pragma unroll
      for (int ua = 0; ua < 2; ++ua)
#pragma unroll
        for (int nt = 0; nt < 2; ++nt) acc[s][ua][nt] = MFMA(aq[ua], bk[nt], acc[s][ua][nt]);
    }
  }

  // block reduction: reuse syT as float scratch [w][s][u][v(28)]
  float* fred = (float*)&syT[0][0];
  __syncthreads();
#pragma unroll
  for (int s = 0; s < 2; ++s)
#pragma unroll
    for (int ua = 0; ua < 2; ++ua)
#pragma unroll
      for (int nt = 0; nt < 2; ++nt)
#pragma unroll
        for (int reg = 0; reg < 4; ++reg) {
          int u = 16 * ua + 4 * quad + reg, v = 16 * nt + m;
          if (u < 27 && v < 27)
            fred[((w * 2 + s) * 27 + u) * 28 + v] = acc[s][ua][nt][reg];
        }
  __syncthreads();
  for (int i = tid; i < 1458; i += 256) {
    int s = i / 729, r = i % 729, u = r / 27, v = r % 27;
    float sum = fred[((0 + s) * 27 + u) * 28 + v] + fred[((2 + s) * 27 + u) * 28 + v] +
                fred[((4 + s) * 27 + u) * 28 + v] + fred[((6 + s) * 27 + u) * 28 + v];
    atomicAdd(&att_raw[(n * 2 + s) * 729 + r], sum);
  }
}

// ---------------------------------------------------------------------------
// K2: fused attention-apply + W_out/BN/res + W_ff/BN/res + tconv/BN/res.
// Block = (n, 6 outputs, 8 slices incl halo), four 2-slice groups, 3 barriers
// each. Wave (mh = w&1, sj = w>>1): M-half x slice-of-group. att finalize
// (tanh) folded into bAtt construction. All weights persistent in registers.
// ---------------------------------------------------------------------------
__global__ __launch_bounds__(256) void k_fused(
    const float* __restrict__ x, const float* __restrict__ att_raw,
    const float* __restrict__ alphas, const float* __restrict__ att0,
    const float* __restrict__ W_out, const float* __restrict__ b_out,
    const float* __restrict__ g_out, const float* __restrict__ be_out,
    const float* __restrict__ m_out, const float* __restrict__ v_out,
    const float* __restrict__ W_ff, const float* __restrict__ b_ff,
    const float* __restrict__ g_ff, const float* __restrict__ be_ff,
    const float* __restrict__ m_ff, const float* __restrict__ v_ff,
    const float* __restrict__ W_t, const float* __restrict__ b_t,
    const float* __restrict__ g_t, const float* __restrict__ be_t,
    const float* __restrict__ m_t, const float* __restrict__ v_t,
    float* __restrict__ out)
{
  __shared__ u16 sY2[59][152];   // y2^T per group: row = sj*27+v, col = s*64+c
  __shared__ u16 sY3[59][72];    // y3^T per group: row = sj*27+v, col = c
  __shared__ u16 sY4[221][72];   // y4^T all 8 slices: row = sl*27+v, col = c
  __shared__ float sBN[6][64];
  const int tid = threadIdx.x, w = tid >> 6, lane = tid & 63;
  const int m = lane & 15, quad = lane >> 4;
  const int mh = w & 1, sj = w >> 1;
  const int n = blockIdx.y, t0 = blockIdx.x * 6;
  const long xb = (long)n * 691200;

  if (tid < 64) {
    int o = tid;
    float sc;
    sc = g_out[o] * rsqrtf(v_out[o] + EPS_); sBN[0][o] = sc; sBN[1][o] = (b_out[o] - m_out[o]) * sc + be_out[o];
    sc = g_ff[o] * rsqrtf(v_ff[o] + EPS_);   sBN[2][o] = sc; sBN[3][o] = (b_ff[o] - m_ff[o]) * sc + be_ff[o];
    sc = g_t[o] * rsqrtf(v_t[o] + EPS_);     sBN[4][o] = sc; sBN[5][o] = (b_t[o] - m_t[o]) * sc + be_t[o];
  }

  // persistent weight A-frags (rows o = 32mh + 16ct + m)
  short8 aWo[2][4], aWf[2][2], aWt[2][6], bAtt[4];
#pragma unroll
  for (int ct = 0; ct < 2; ++ct) {
#pragma unroll
    for (int kf = 0; kf < 4; ++kf) {
      short8 tt;
#pragma unroll
      for (int j = 0; j < 8; ++j)
        tt[j] = (short)f2u(W_out[(32 * mh + 16 * ct + m) * 128 + 32 * kf + 8 * quad + j]);
      aWo[ct][kf] = tt;
    }
#pragma unroll
    for (int kf = 0; kf < 2; ++kf) {
      short8 tt;
#pragma unroll
      for (int j = 0; j < 8; ++j)
        tt[j] = (short)f2u(W_ff[(32 * mh + 16 * ct + m) * 64 + 32 * kf + 8 * quad + j]);
      aWf[ct][kf] = tt;
    }
#pragma unroll
    for (int kf = 0; kf < 6; ++kf) {  // k = dt*64 + ih*32 + 8quad + j
      int dt = kf >> 1, ih = kf & 1;
      short8 tt;
#pragma unroll
      for (int j = 0; j < 8; ++j)
        tt[j] = (short)f2u(W_t[((32 * mh + 16 * ct + m) * 64 + 32 * ih + 8 * quad + j) * 3 + dt]);
      aWt[ct][kf] = tt;
    }
  }
  // att finalize folded in: bAtt[2s+nt][j] = att[s][u=8quad+j][v=16nt+m]
#pragma unroll
  for (int s = 0; s < 2; ++s)
#pragma unroll
    for (int nt = 0; nt < 2; ++nt) {
      short8 tt;
#pragma unroll
      for (int j = 0; j < 8; ++j) {
        int u = 8 * quad + j, v = 16 * nt + m;
        float av = 0.f;
        if (u < 27 && v < 27)
          av = tanhf(att_raw[(n * 2 + s) * 729 + u * 27 + v] * (1.f / 6400.f)) * alphas[s] +
               att0[s * 729 + u * 27 + v];
        tt[j] = (short)f2u(av);
      }
      bAtt[s * 2 + nt] = tt;
    }
  __syncthreads();

  for (int g = 0; g < 4; ++g) {
    const int sl = 2 * g + sj, t = t0 - 1 + sl;
    const bool valid = (t >= 0) && (t < 400);
    // S2: y2 = x . att  -> sY2
    if (valid) {
#pragma unroll
      for (int ct = 0; ct < 2; ++ct) {
        short8 ax;
#pragma unroll
        for (int j = 0; j < 8; ++j) {
          int u = 8 * quad + j;
          ax[j] = (u < 27) ? (short)f2u(x[xb + (long)(32 * mh + 16 * ct + m) * 10800 + t * 27 + u])
                           : (short)0;
        }
#pragma unroll
        for (int s = 0; s < 2; ++s)
#pragma unroll
          for (int nt = 0; nt < 2; ++nt) {
            f32x4 d = MFMA(ax, bAtt[s * 2 + nt], z4());
            int v = 16 * nt + m;
            if (v < 27) {
              short4_t pk;
#pragma unroll
              for (int reg = 0; reg < 4; ++reg) pk[reg] = (short)f2u(d[reg]);
              *(short4_t*)&sY2[sj * 27 + v][64 * s + 32 * mh + 16 * ct + 4 * quad] = pk;
            }
          }
      }
    }
    __syncthreads();
    // S3: y3 = lrelu(x + bn(W_out @ y2)), full K=128
    if (valid) {
      f32x4 oc[2][2];
#pragma unroll
      for (int ct = 0; ct < 2; ++ct)
#pragma unroll
        for (int nt = 0; nt < 2; ++nt) oc[ct][nt] = z4();
#pragma unroll
      for (int kf = 0; kf < 4; ++kf)
#pragma unroll
        for (int nt = 0; nt < 2; ++nt) {
          short8 b = *(const short8*)&sY2[sj * 27 + 16 * nt + m][32 * kf + 8 * quad];
#pragma unroll
          for (int ct = 0; ct < 2; ++ct) oc[ct][nt] = MFMA(aWo[ct][kf], b, oc[ct][nt]);
        }
#pragma unroll
      for (int ct = 0; ct < 2; ++ct)
#pragma unroll
        for (int nt = 0; nt < 2; ++nt) {
          int v = 16 * nt + m;
          if (v < 27) {
            short4_t pk;
#pragma unroll
            for (int reg = 0; reg < 4; ++reg) {
              int o = 32 * mh + 16 * ct + 4 * quad + reg;
              float r = x[xb + (long)o * 10800 + t * 27 + v] + oc[ct][nt][reg] * sBN[0][o] + sBN[1][o];
              pk[reg] = (short)f2u((r >= 0.f) ? r : LEAK * r);
            }
            *(short4_t*)&sY3[sj * 27 + v][32 * mh + 16 * ct + 4 * quad] = pk;
          }
        }
    }
    __syncthreads();
    // S4: y4 = lrelu(x + bn(W_ff @ y3)) -> sY4 (or zeros for invalid t)
    if (valid) {
      f32x4 fc[2][2];
#pragma unroll
      for (int ct = 0; ct < 2; ++ct)
#pragma unroll
        for (int nt = 0; nt < 2; ++nt) fc[ct][nt] = z4();
#pragma unroll
      for (int kf = 0; kf < 2; ++kf)
#pragma unroll
        for (int nt = 0; nt < 2; ++nt) {
          short8 b = *(const short8*)&sY3[sj * 27 + 16 * nt + m][32 * kf + 8 * quad];
#pragma unroll
          for (int ct = 0; ct < 2; ++ct) fc[ct][nt] = MFMA(aWf[ct][kf], b, fc[ct][nt]);
        }
#pragma unroll
      for (int ct = 0; ct < 2; ++ct)
#pragma unroll
        for (int nt = 0; nt < 2; ++nt) {
          int v = 16 * nt + m;
          if (v < 27) {
            short4_t pk;
#pragma unroll
            for (int reg = 0; reg < 4; ++reg) {
              int o = 32 * mh + 16 * ct + 4 * quad + reg;
              float r = x[xb + (long)o * 10800 + t * 27 + v] + fc[ct][nt][reg] * sBN[2][o] + sBN[3][o];
              pk[reg] = (short)f2u((r >= 0.f) ? r : LEAK * r);
            }
            *(short4_t*)&sY4[sl * 27 + v][32 * mh + 16 * ct + 4 * quad] = pk;
          }
        }
    } else {
      short4_t zz = {0, 0, 0, 0};
      for (int i = lane; i < 27 * 8; i += 64)
        *(short4_t*)&sY4[sl * 27 + (i >> 3)][32 * mh + 4 * (i & 7)] = zz;
    }
    __syncthreads();
  }

  // conv phase: wave (mh, qh = w>>1) does outputs q = 3*qh + {0,1,2}
  const int qh = w >> 1;
  for (int qq = 0; qq < 3; ++qq) {
    const int q = qh * 3 + qq, t_out = t0 + q;
    f32x4 cc2[2][2];
#pragma unroll
    for (int ct = 0; ct < 2; ++ct)
#pragma unroll
      for (int nt = 0; nt < 2; ++nt) cc2[ct][nt] = z4();
#pragma unroll
    for (int kf = 0; kf < 6; ++kf) {
      int dt = kf >> 1, ih = kf & 1;
#pragma unroll
      for (int nt = 0; nt < 2; ++nt) {
        short8 b = *(const short8*)&sY4[(q + dt) * 27 + 16 * nt + m][32 * ih + 8 * quad];
#pragma unroll
        for (int ct = 0; ct < 2; ++ct) cc2[ct][nt] = MFMA(aWt[ct][kf], b, cc2[ct][nt]);
      }
    }
    if (t_out < 400) {
#pragma unroll
      for (int ct = 0; ct < 2; ++ct)
#pragma unroll
        for (int nt = 0; nt < 2; ++nt) {
          int v = 16 * nt + m;
          if (v < 27) {
#pragma unroll
            for (int reg = 0; reg < 4; ++reg) {
              int o = 32 * mh + 16 * ct + 4 * quad + reg;
              float r = u2f(sY4[(q + 1) * 27 + v][o]) + cc2[ct][nt][reg] * sBN[4][o] + sBN[5][o];
              out[(long)(n * 64 + o) * 10800 + t_out * 27 + v] = (r >= 0.f) ? r : LEAK * r;
            }
          }
        }
    }
  }
}

// ---------------------------------------------------------------------------
extern "C" void kernel_launch(void* const* d_in, const int* in_sizes, int n_in,
                              void* d_out, int out_size, void* d_ws, size_t ws_size,
                              hipStream_t stream)
{
  const float* x      = (const float*)d_in[0];
  const float* pe     = (const float*)d_in[1];
  const float* W_in   = (const float*)d_in[2];
  const float* b_in   = (const float*)d_in[3];
  const float* alphas = (const float*)d_in[4];
  const float* att0   = (const float*)d_in[5];
  const float* W_out  = (const float*)d_in[6];
  const float* b_out  = (const float*)d_in[7];
  const float* g_out  = (const float*)d_in[8];
  const float* be_out = (const float*)d_in[9];
  const float* m_out  = (const float*)d_in[10];
  const float* v_out  = (const float*)d_in[11];
  const float* W_ff   = (const float*)d_in[12];
  const float* b_ff   = (const float*)d_in[13];
  const float* g_ff   = (const float*)d_in[14];
  const float* be_ff  = (const float*)d_in[15];
  const float* m_ff   = (const float*)d_in[16];
  const float* v_ff   = (const float*)d_in[17];
  const float* W_t    = (const float*)d_in[18];
  const float* b_t    = (const float*)d_in[19];
  const float* g_t    = (const float*)d_in[20];
  const float* be_t   = (const float*)d_in[21];
  const float* m_t    = (const float*)d_in[22];
  const float* v_t    = (const float*)d_in[23];

  float* att_raw = (float*)d_ws;  // 32*2*729 floats = 186 KB

  hipMemsetAsync(att_raw, 0, 32 * 2 * 729 * sizeof(float), stream);
  k_att<<<dim3(50, 32), 256, 0, stream>>>(x, pe, W_in, b_in, att_raw);
  k_fused<<<dim3(67, 32), 256, 0, stream>>>(
      x, att_raw, alphas, att0,
      W_out, b_out, g_out, be_out, m_out, v_out,
      W_ff, b_ff, g_ff, be_ff, m_ff, v_ff,
      W_t, b_t, g_t, be_t, m_t, v_t,
      (float*)d_out);
}

// Round 6
// 488.311 us; speedup vs baseline: 1.0156x; 1.0156x over previous
//
#include <hip/hip_runtime.h>
#include <hip/hip_bf16.h>

typedef __hip_bfloat16 bf16;
typedef unsigned short u16;
typedef __attribute__((ext_vector_type(4))) short short4_t;
typedef __attribute__((ext_vector_type(8))) short short8;
typedef __attribute__((ext_vector_type(4))) float f32x4;

#define LEAK 0.1f
#define EPS_ 1e-5f
#define MFMA(a, b, c) __builtin_amdgcn_mfma_f32_16x16x32_bf16(a, b, c, 0, 0, 0)
// N=32 C=64 T=400 V=27 S=2 IC=16 O=64 -- fp32 I/O, bf16 MFMA internally

__device__ __forceinline__ float u2f(u16 u) { return __uint_as_float(((unsigned int)u) << 16); }
__device__ __forceinline__ u16 f2u(float f) {
  bf16 h = __float2bfloat16(f);
  u16 r;
  __builtin_memcpy(&r, &h, 2);
  return r;
}
__device__ __forceinline__ f32x4 z4() { f32x4 z = {0.f, 0.f, 0.f, 0.f}; return z; }
__device__ __forceinline__ short8 z8() { short8 z = {0, 0, 0, 0, 0, 0, 0, 0}; return z; }

// ---------------------------------------------------------------------------
// K_att: logits. Block=(n, 8 t). Coalesced stage of (x+pe)^T -> one barrier ->
// wave-private slices {w, w+4}: qk GEMM, pack qk^T OVER the staging region
// (disjoint-row hazard-free), logit MFMAs accumulate in regs. Block-reduce,
// 1458 atomics/block. LDS 37 KB, no intra-loop barriers.
// ---------------------------------------------------------------------------
__global__ __launch_bounds__(256, 4) void k_att(
    const float* __restrict__ x, const float* __restrict__ pe,
    const float* __restrict__ W_in, const float* __restrict__ b_in,
    float* __restrict__ att_raw)
{
  __shared__ u16 syT[8][32][72];  // per-slice [v][c] (x+pe)^T; later qk^T [v][r]
  __shared__ float sb[64];
  const int tid = threadIdx.x, w = tid >> 6, lane = tid & 63;
  const int m = lane & 15, quad = lane >> 4;
  const int n = blockIdx.y, t0 = blockIdx.x * 8;
  const long xb = (long)n * 691200 + t0 * 27;

  for (int i = tid; i < 8 * 5 * 72; i += 256) {  // zero pad rows 27..31
    int sl = i / 360, r = i % 360;
    syT[sl][27 + r / 72][r % 72] = 0;
  }
  short8 aWin[4][2];
#pragma unroll
  for (int mt = 0; mt < 4; ++mt)
#pragma unroll
    for (int kf = 0; kf < 2; ++kf) {
      short8 tt;
#pragma unroll
      for (int j = 0; j < 8; ++j)
        tt[j] = (short)f2u(W_in[(16 * mt + m) * 64 + 32 * kf + 8 * quad + j]);
      aWin[mt][kf] = tt;
    }
  if (tid < 64) sb[tid] = b_in[tid];

  for (int i = tid; i < 64 * 216; i += 256) {  // coalesced staging
    int c = i / 216, f = i % 216;
    syT[f / 27][f % 27][c] = f2u(x[xb + (long)c * 10800 + f] + pe[c * 10800 + t0 * 27 + f]);
  }
  __syncthreads();

  f32x4 accL[2][2][2];
#pragma unroll
  for (int s = 0; s < 2; ++s)
#pragma unroll
    for (int a = 0; a < 2; ++a)
#pragma unroll
      for (int b = 0; b < 2; ++b) accL[s][a][b] = z4();

#pragma unroll
  for (int ss = 0; ss < 2; ++ss) {
    const int sl = w + 4 * ss;
    // qk GEMM: all B-frags first, then MFMAs, then overlay pack
    short8 bf[2][2];
#pragma unroll
    for (int nt = 0; nt < 2; ++nt)
#pragma unroll
      for (int kf = 0; kf < 2; ++kf)
        bf[nt][kf] = *(const short8*)&syT[sl][16 * nt + m][32 * kf + 8 * quad];
    f32x4 q[4][2];
#pragma unroll
    for (int mt = 0; mt < 4; ++mt)
#pragma unroll
      for (int nt = 0; nt < 2; ++nt) {
        q[mt][nt] = MFMA(aWin[mt][0], bf[nt][0], z4());
        q[mt][nt] = MFMA(aWin[mt][1], bf[nt][1], q[mt][nt]);
      }
#pragma unroll
    for (int nt = 0; nt < 2; ++nt) {
      int v = 16 * nt + m;
      if (v < 27) {
#pragma unroll
        for (int mt = 0; mt < 4; ++mt) {
          short4_t pk;
#pragma unroll
          for (int reg = 0; reg < 4; ++reg)
            pk[reg] = (short)f2u(q[mt][nt][reg] + sb[16 * mt + 4 * quad + reg]);
          *(short4_t*)&syT[sl][v][16 * mt + 4 * quad] = pk;
        }
      }
    }
    __asm__ volatile("s_waitcnt lgkmcnt(0)" ::: "memory");
    // logits: A = q^T (K=16 real), B = k
#pragma unroll
    for (int s = 0; s < 2; ++s) {
      short8 aq[2], bk[2];
#pragma unroll
      for (int ua = 0; ua < 2; ++ua)
        aq[ua] = (quad < 2) ? *(const short8*)&syT[sl][16 * ua + m][16 * s + 8 * quad] : z8();
#pragma unroll
      for (int nt = 0; nt < 2; ++nt)
        bk[nt] = (quad < 2) ? *(const short8*)&syT[sl][16 * nt + m][32 + 16 * s + 8 * quad] : z8();
#pragma unroll
      for (int ua = 0; ua < 2; ++ua)
#pragma unroll
        for (int nt = 0; nt < 2; ++nt) accL[s][ua][nt] = MFMA(aq[ua], bk[nt], accL[s][ua][nt]);
    }
  }

  float* fred = (float*)&syT[0][0][0];  // [8][27][28]
  __syncthreads();
#pragma unroll
  for (int s = 0; s < 2; ++s)
#pragma unroll
    for (int ua = 0; ua < 2; ++ua)
#pragma unroll
      for (int nt = 0; nt < 2; ++nt)
#pragma unroll
        for (int reg = 0; reg < 4; ++reg) {
          int u = 16 * ua + 4 * quad + reg, v = 16 * nt + m;
          if (u < 27 && v < 27) fred[((w * 2 + s) * 27 + u) * 28 + v] = accL[s][ua][nt][reg];
        }
  __syncthreads();
  for (int i = tid; i < 1458; i += 256) {
    int s = i / 729, r = i % 729, u = r / 27, v = r % 27;
    float sum = fred[((0 + s) * 27 + u) * 28 + v] + fred[((2 + s) * 27 + u) * 28 + v] +
                fred[((4 + s) * 27 + u) * 28 + v] + fred[((6 + s) * 27 + u) * 28 + v];
    atomicAdd(&att_raw[(n * 2 + s) * 729 + r], sum);
  }
}

// ---------------------------------------------------------------------------
// K_fin: finalize att in-place (fp32) and optionally write transposed bf16
// attT[n][s][v(32)][u(32)] for K_mid's B-frags (pads pre-zeroed by memset).
// ---------------------------------------------------------------------------
__global__ __launch_bounds__(256) void k_att_fin(
    float* __restrict__ att, const float* __restrict__ alphas,
    const float* __restrict__ att0, u16* __restrict__ attT)
{
  int i = blockIdx.x * 256 + threadIdx.x;
  if (i >= 32 * 2 * 729) return;
  int ns = i / 729, s = ns & 1, r = i % 729, u = r / 27, v = r % 27;
  float fin = tanhf(att[i] * (1.f / 6400.f)) * alphas[s] + att0[s * 729 + r];
  att[i] = fin;
  if (attT) attT[(ns * 32 + v) * 32 + u] = f2u(fin);
}

// ---------------------------------------------------------------------------
// K_mid: y2 -> y3 -> y4(ws, bf16 [n][t][v][c]). Block=(n, 8 t), 4 phases of 2
// slices; wave (mh = w&1, sp = w>>1) owns channel-half x slice-of-pair.
// 2 barriers per phase. LDS 27.6 KB -> 5 blocks/CU.
// ---------------------------------------------------------------------------
__global__ __launch_bounds__(256, 4) void k_mid(
    const float* __restrict__ x, const u16* __restrict__ attT,
    const float* __restrict__ W_out, const float* __restrict__ b_out,
    const float* __restrict__ g_out, const float* __restrict__ be_out,
    const float* __restrict__ m_out, const float* __restrict__ v_out,
    const float* __restrict__ W_ff, const float* __restrict__ b_ff,
    const float* __restrict__ g_ff, const float* __restrict__ be_ff,
    const float* __restrict__ m_ff, const float* __restrict__ v_ff,
    u16* __restrict__ y4w)
{
  __shared__ u16 sy2[2][32][136];  // [sp][v][s*64+c]
  __shared__ u16 sy3[2][32][72];   // [sp][v][c]
  __shared__ float sBN[4][64];
  const int tid = threadIdx.x, w = tid >> 6, lane = tid & 63;
  const int m = lane & 15, quad = lane >> 4;
  const int mh = w & 1, sp = w >> 1;
  const int n = blockIdx.y, t0 = blockIdx.x * 8;
  const long xb = (long)n * 691200;

  for (int i = tid; i < 2 * 5 * 136; i += 256) {  // zero pad rows 27..31
    int p = i / 680, r = i % 680;
    sy2[p][27 + r / 136][r % 136] = 0;
  }
  for (int i = tid; i < 2 * 5 * 72; i += 256) {
    int p = i / 360, r = i % 360;
    sy3[p][27 + r / 72][r % 72] = 0;
  }
  if (tid < 64) {
    int o = tid;
    float sc;
    sc = g_out[o] * rsqrtf(v_out[o] + EPS_); sBN[0][o] = sc; sBN[1][o] = (b_out[o] - m_out[o]) * sc + be_out[o];
    sc = g_ff[o] * rsqrtf(v_ff[o] + EPS_);   sBN[2][o] = sc; sBN[3][o] = (b_ff[o] - m_ff[o]) * sc + be_ff[o];
  }
  short8 aWo[2][4], aWf[2][2];
#pragma unroll
  for (int ct = 0; ct < 2; ++ct) {
#pragma unroll
    for (int kf = 0; kf < 4; ++kf) {
      short8 tt;
#pragma unroll
      for (int j = 0; j < 8; ++j)
        tt[j] = (short)f2u(W_out[(32 * mh + 16 * ct + m) * 128 + 32 * kf + 8 * quad + j]);
      aWo[ct][kf] = tt;
    }
#pragma unroll
    for (int kf = 0; kf < 2; ++kf) {
      short8 tt;
#pragma unroll
      for (int j = 0; j < 8; ++j)
        tt[j] = (short)f2u(W_ff[(32 * mh + 16 * ct + m) * 64 + 32 * kf + 8 * quad + j]);
      aWf[ct][kf] = tt;
    }
  }
  __syncthreads();

  for (int g = 0; g < 4; ++g) {
    const int sl = 2 * g + sp, t = t0 + sl;
    // S2: y2 = x . att  (A-frags from global x, B-frags from global attT)
    short8 ax[2];
#pragma unroll
    for (int ct = 0; ct < 2; ++ct) {
      short8 tt;
#pragma unroll
      for (int j = 0; j < 8; ++j) {
        int u = 8 * quad + j;
        int uu = (u < 27) ? u : 0;
        float xv = x[xb + (long)(32 * mh + 16 * ct + m) * 10800 + t * 27 + uu];
        tt[j] = (u < 27) ? (short)f2u(xv) : (short)0;
      }
      ax[ct] = tt;
    }
#pragma unroll
    for (int s = 0; s < 2; ++s) {
      short8 batt[2];
#pragma unroll
      for (int nt = 0; nt < 2; ++nt)
        batt[nt] = *(const short8*)&attT[((n * 2 + s) * 32 + 16 * nt + m) * 32 + 8 * quad];
      f32x4 a2[2][2];
#pragma unroll
      for (int ct = 0; ct < 2; ++ct)
#pragma unroll
        for (int nt = 0; nt < 2; ++nt) a2[ct][nt] = MFMA(ax[ct], batt[nt], z4());
#pragma unroll
      for (int ct = 0; ct < 2; ++ct)
#pragma unroll
        for (int nt = 0; nt < 2; ++nt) {
          int v = 16 * nt + m;
          if (v < 27) {
            short4_t pk;
#pragma unroll
            for (int reg = 0; reg < 4; ++reg) pk[reg] = (short)f2u(a2[ct][nt][reg]);
            *(short4_t*)&sy2[sp][v][64 * s + 32 * mh + 16 * ct + 4 * quad] = pk;
          }
        }
    }
    __syncthreads();
    // S3: y3 = lrelu(x + bn(W_out @ y2)), K=128
    {
      f32x4 a3[2][2];
#pragma unroll
      for (int ct = 0; ct < 2; ++ct)
#pragma unroll
        for (int nt = 0; nt < 2; ++nt) a3[ct][nt] = z4();
#pragma unroll
      for (int kf = 0; kf < 4; ++kf)
#pragma unroll
        for (int nt = 0; nt < 2; ++nt) {
          short8 b = *(const short8*)&sy2[sp][16 * nt + m][32 * kf + 8 * quad];
#pragma unroll
          for (int ct = 0; ct < 2; ++ct) a3[ct][nt] = MFMA(aWo[ct][kf], b, a3[ct][nt]);
        }
#pragma unroll
      for (int ct = 0; ct < 2; ++ct)
#pragma unroll
        for (int nt = 0; nt < 2; ++nt) {
          int v = 16 * nt + m;
          if (v < 27) {
            short4_t pk;
#pragma unroll
            for (int reg = 0; reg < 4; ++reg) {
              int o = 32 * mh + 16 * ct + 4 * quad + reg;
              float r = x[xb + (long)o * 10800 + t * 27 + v] + a3[ct][nt][reg] * sBN[0][o] + sBN[1][o];
              pk[reg] = (short)f2u((r >= 0.f) ? r : LEAK * r);
            }
            *(short4_t*)&sy3[sp][v][32 * mh + 16 * ct + 4 * quad] = pk;
          }
        }
    }
    __syncthreads();
    // S4: y4 = lrelu(x + bn(W_ff @ y3)) -> ws bf16 [n][t][v][c]
    {
      f32x4 a4[2][2];
#pragma unroll
      for (int ct = 0; ct < 2; ++ct)
#pragma unroll
        for (int nt = 0; nt < 2; ++nt) a4[ct][nt] = z4();
#pragma unroll
      for (int kf = 0; kf < 2; ++kf)
#pragma unroll
        for (int nt = 0; nt < 2; ++nt) {
          short8 b = *(const short8*)&sy3[sp][16 * nt + m][32 * kf + 8 * quad];
#pragma unroll
          for (int ct = 0; ct < 2; ++ct) a4[ct][nt] = MFMA(aWf[ct][kf], b, a4[ct][nt]);
        }
#pragma unroll
      for (int ct = 0; ct < 2; ++ct)
#pragma unroll
        for (int nt = 0; nt < 2; ++nt) {
          int v = 16 * nt + m;
          if (v < 27) {
            short4_t pk;
#pragma unroll
            for (int reg = 0; reg < 4; ++reg) {
              int o = 32 * mh + 16 * ct + 4 * quad + reg;
              float r = x[xb + (long)o * 10800 + t * 27 + v] + a4[ct][nt][reg] * sBN[2][o] + sBN[3][o];
              pk[reg] = (short)f2u((r >= 0.f) ? r : LEAK * r);
            }
            *(short4_t*)&y4w[((long)(n * 400 + t) * 27 + v) * 64 + 32 * mh + 16 * ct + 4 * quad] = pk;
          }
        }
    }
  }
}

// ---------------------------------------------------------------------------
// K_conv: z = lrelu(y4 + bn(conv3 @ y4)). Block=(n, 8 t), wave (mh, sp) does
// slices {2g+sp}. NO LDS, NO barriers; B-frags + residual straight from ws.
// K = 192 exact (no padding waste).
// ---------------------------------------------------------------------------
__global__ __launch_bounds__(256, 4) void k_conv(
    const u16* __restrict__ y4w, const float* __restrict__ W_t,
    const float* __restrict__ b_t, const float* __restrict__ g_t,
    const float* __restrict__ be_t, const float* __restrict__ m_t,
    const float* __restrict__ v_t, float* __restrict__ out)
{
  const int tid = threadIdx.x, w = tid >> 6, lane = tid & 63;
  const int m = lane & 15, quad = lane >> 4;
  const int mh = w & 1, sp = w >> 1;
  const int n = blockIdx.y, t0 = blockIdx.x * 8;

  short8 aWt[2][6];  // kf = 2*dt + ih
#pragma unroll
  for (int ct = 0; ct < 2; ++ct)
#pragma unroll
    for (int kf = 0; kf < 6; ++kf) {
      int dt = kf >> 1, ih = kf & 1;
      short8 tt;
#pragma unroll
      for (int j = 0; j < 8; ++j)
        tt[j] = (short)f2u(W_t[((32 * mh + 16 * ct + m) * 64 + 32 * ih + 8 * quad + j) * 3 + dt]);
      aWt[ct][kf] = tt;
    }
  float At[2][4], Bt[2][4];
#pragma unroll
  for (int ct = 0; ct < 2; ++ct)
#pragma unroll
    for (int reg = 0; reg < 4; ++reg) {
      int o = 32 * mh + 16 * ct + 4 * quad + reg;
      float sc = g_t[o] * rsqrtf(v_t[o] + EPS_);
      At[ct][reg] = sc;
      Bt[ct][reg] = (b_t[o] - m_t[o]) * sc + be_t[o];
    }

  for (int g = 0; g < 4; ++g) {
    const int sl = 2 * g + sp, t = t0 + sl;
    f32x4 ac[2][2];
#pragma unroll
    for (int ct = 0; ct < 2; ++ct)
#pragma unroll
      for (int nt = 0; nt < 2; ++nt) ac[ct][nt] = z4();
#pragma unroll
    for (int dt = 0; dt < 3; ++dt) {
      int tp = t - 1 + dt;
      bool ok = (tp >= 0) && (tp < 400);
#pragma unroll
      for (int ih = 0; ih < 2; ++ih)
#pragma unroll
        for (int nt = 0; nt < 2; ++nt) {
          short8 b = ok ? *(const short8*)&y4w[((long)(n * 400 + tp) * 27 + 16 * nt + m) * 64 +
                                               32 * ih + 8 * quad]
                        : z8();
#pragma unroll
          for (int ct = 0; ct < 2; ++ct) ac[ct][nt] = MFMA(aWt[ct][2 * dt + ih], b, ac[ct][nt]);
        }
    }
#pragma unroll
    for (int ct = 0; ct < 2; ++ct)
#pragma unroll
      for (int nt = 0; nt < 2; ++nt) {
        int v = 16 * nt + m;
        if (v < 27) {
          short4_t ry = *(const short4_t*)&y4w[((long)(n * 400 + t) * 27 + v) * 64 +
                                               32 * mh + 16 * ct + 4 * quad];
#pragma unroll
          for (int reg = 0; reg < 4; ++reg) {
            int o = 32 * mh + 16 * ct + 4 * quad + reg;
            float r = u2f(ry[reg]) + ac[ct][nt][reg] * At[ct][reg] + Bt[ct][reg];
            out[(long)(n * 64 + o) * 10800 + t * 27 + v] = (r >= 0.f) ? r : LEAK * r;
          }
        }
      }
  }
}

// ---------------------------------------------------------------------------
// Fallback (ws too small): R4's verified fused kernel, reads finalized att.
// ---------------------------------------------------------------------------
__global__ __launch_bounds__(256) void k_fused_fb(
    const float* __restrict__ x, const float* __restrict__ att,
    const float* __restrict__ W_out, const float* __restrict__ b_out,
    const float* __restrict__ g_out, const float* __restrict__ be_out,
    const float* __restrict__ m_out, const float* __restrict__ v_out,
    const float* __restrict__ W_ff, const float* __restrict__ b_ff,
    const float* __restrict__ g_ff, const float* __restrict__ be_ff,
    const float* __restrict__ m_ff, const float* __restrict__ v_ff,
    const float* __restrict__ W_t, const float* __restrict__ b_t,
    const float* __restrict__ g_t, const float* __restrict__ be_t,
    const float* __restrict__ m_t, const float* __restrict__ v_t,
    float* __restrict__ out)
{
  __shared__ u16 sx[64][40];
  __shared__ u16 sy2[32][136];
  __shared__ u16 sy3[32][72];
  __shared__ u16 sy4[3][32][72];
  const int tid = threadIdx.x;
  const int w = tid >> 6, lane = tid & 63;
  const int m = lane & 15, quad = lane >> 4;
  const int n = blockIdx.y, t0 = blockIdx.x * 8;

  for (int i = tid; i < 64 * 40; i += 256) sx[0][i] = 0;
  for (int i = tid; i < 32 * 136; i += 256) sy2[0][i] = 0;
  for (int i = tid; i < 32 * 72; i += 256) sy3[0][i] = 0;
  for (int i = tid; i < 3 * 32 * 72; i += 256) sy4[0][0][i] = 0;

  short8 aWo[4], aWf[2], aWt[6], bAtt[4];
#pragma unroll
  for (int kf = 0; kf < 4; ++kf) {
    short8 tt;
#pragma unroll
    for (int j = 0; j < 8; ++j)
      tt[j] = (short)f2u(W_out[(16 * w + m) * 128 + 32 * kf + 8 * quad + j]);
    aWo[kf] = tt;
  }
#pragma unroll
  for (int kf = 0; kf < 2; ++kf) {
    short8 tt;
#pragma unroll
    for (int j = 0; j < 8; ++j)
      tt[j] = (short)f2u(W_ff[(16 * w + m) * 64 + 32 * kf + 8 * quad + j]);
    aWf[kf] = tt;
  }
#pragma unroll
  for (int kf = 0; kf < 6; ++kf) {
    short8 tt;
    int dt = kf >> 1;
#pragma unroll
    for (int j = 0; j < 8; ++j) {
      int ii = 32 * (kf & 1) + 8 * quad + j;
      tt[j] = (short)f2u(W_t[((16 * w + m) * 64 + ii) * 3 + dt]);
    }
    aWt[kf] = tt;
  }
#pragma unroll
  for (int s = 0; s < 2; ++s)
#pragma unroll
    for (int nt = 0; nt < 2; ++nt) {
      short8 tt;
#pragma unroll
      for (int j = 0; j < 8; ++j) {
        int u = 8 * quad + j, v = 16 * nt + m;
        int idx = (n * 2 + s) * 729 + ((u < 27) ? u : 0) * 27 + ((v < 27) ? v : 0);
        tt[j] = (u < 27 && v < 27) ? (short)f2u(att[idx]) : (short)0;
      }
      bAtt[s * 2 + nt] = tt;
    }
  float Ao[4], Bo[4], Af[4], Bf[4], At[4], Bt[4];
#pragma unroll
  for (int reg = 0; reg < 4; ++reg) {
    int o = 16 * w + quad * 4 + reg;
    float sc;
    sc = g_out[o] * rsqrtf(v_out[o] + EPS_); Ao[reg] = sc; Bo[reg] = (b_out[o] - m_out[o]) * sc + be_out[o];
    sc = g_ff[o] * rsqrtf(v_ff[o] + EPS_);   Af[reg] = sc; Bf[reg] = (b_ff[o] - m_ff[o]) * sc + be_ff[o];
    sc = g_t[o] * rsqrtf(v_t[o] + EPS_);     At[reg] = sc; Bt[reg] = (b_t[o] - m_t[o]) * sc + be_t[o];
  }
  __syncthreads();

  for (int st = 0; st < 10; ++st) {
    const int t = t0 - 1 + st;
    const bool valid = (t >= 0) && (t < 400);
    if (valid) {
      for (int i = tid; i < 1728; i += 256) {
        int c = i / 27, u = i % 27;
        sx[c][u] = f2u(x[((n * 64 + c) * 400 + t) * 27 + u]);
      }
    }
    __syncthreads();
    if (valid) {
      short8 ax = *(const short8*)&sx[16 * w + m][8 * quad];
      f32x4 acc[4];
#pragma unroll
      for (int f = 0; f < 4; ++f) acc[f] = MFMA(ax, bAtt[f], z4());
#pragma unroll
      for (int s = 0; s < 2; ++s)
#pragma unroll
        for (int nt = 0; nt < 2; ++nt) {
          int v = 16 * nt + m;
          if (v < 27) {
            f32x4 a = acc[s * 2 + nt];
#pragma unroll
            for (int reg = 0; reg < 4; ++reg)
              sy2[v][s * 64 + 16 * w + quad * 4 + reg] = f2u(a[reg]);
          }
        }
    }
    __syncthreads();
    if (valid) {
      f32x4 a0 = z4(), a1 = z4();
#pragma unroll
      for (int kf = 0; kf < 4; ++kf) {
        short8 b0 = *(const short8*)&sy2[m][32 * kf + 8 * quad];
        short8 b1 = *(const short8*)&sy2[16 + m][32 * kf + 8 * quad];
        a0 = MFMA(aWo[kf], b0, a0);
        a1 = MFMA(aWo[kf], b1, a1);
      }
#pragma unroll
      for (int nt = 0; nt < 2; ++nt) {
        f32x4 a = nt ? a1 : a0;
        int v = 16 * nt + m;
        if (v < 27) {
#pragma unroll
          for (int reg = 0; reg < 4; ++reg) {
            int o = 16 * w + quad * 4 + reg;
            float r = u2f(sx[o][v]) + a[reg] * Ao[reg] + Bo[reg];
            sy3[v][o] = f2u((r >= 0.f) ? r : LEAK * r);
          }
        }
      }
    }
    __syncthreads();
    if (valid) {
      f32x4 a0 = z4(), a1 = z4();
#pragma unroll
      for (int kf = 0; kf < 2; ++kf) {
        short8 b0 = *(const short8*)&sy3[m][32 * kf + 8 * quad];
        short8 b1 = *(const short8*)&sy3[16 + m][32 * kf + 8 * quad];
        a0 = MFMA(aWf[kf], b0, a0);
        a1 = MFMA(aWf[kf], b1, a1);
      }
#pragma unroll
      for (int nt = 0; nt < 2; ++nt) {
        f32x4 a = nt ? a1 : a0;
        int v = 16 * nt + m;
        if (v < 27) {
#pragma unroll
          for (int reg = 0; reg < 4; ++reg) {
            int o = 16 * w + quad * 4 + reg;
            float r = u2f(sx[o][v]) + a[reg] * Af[reg] + Bf[reg];
            sy4[st % 3][v][o] = f2u((r >= 0.f) ? r : LEAK * r);
          }
        }
      }
    } else {
      for (int i = tid; i < 27 * 64; i += 256)
        sy4[st % 3][i / 64][i % 64] = 0;
    }
    __syncthreads();
    if (st >= 2) {
      f32x4 a0 = z4(), a1 = z4();
#pragma unroll
      for (int kf = 0; kf < 6; ++kf) {
        int sl = (st - 2 + (kf >> 1)) % 3;
        int col = 32 * (kf & 1) + 8 * quad;
        short8 b0 = *(const short8*)&sy4[sl][m][col];
        short8 b1 = *(const short8*)&sy4[sl][16 + m][col];
        a0 = MFMA(aWt[kf], b0, a0);
        a1 = MFMA(aWt[kf], b1, a1);
      }
      int t_out = t0 + st - 2;
#pragma unroll
      for (int nt = 0; nt < 2; ++nt) {
        f32x4 a = nt ? a1 : a0;
        int v = 16 * nt + m;
        if (v < 27) {
#pragma unroll
          for (int reg = 0; reg < 4; ++reg) {
            int o = 16 * w + quad * 4 + reg;
            float r = u2f(sy4[(st - 1) % 3][v][o]) + a[reg] * At[reg] + Bt[reg];
            out[((n * 64 + o) * 400 + t_out) * 27 + v] = (r >= 0.f) ? r : LEAK * r;
          }
        }
      }
    }
  }
}

// ---------------------------------------------------------------------------
extern "C" void kernel_launch(void* const* d_in, const int* in_sizes, int n_in,
                              void* d_out, int out_size, void* d_ws, size_t ws_size,
                              hipStream_t stream)
{
  const float* x      = (const float*)d_in[0];
  const float* pe     = (const float*)d_in[1];
  const float* W_in   = (const float*)d_in[2];
  const float* b_in   = (const float*)d_in[3];
  const float* alphas = (const float*)d_in[4];
  const float* att0   = (const float*)d_in[5];
  const float* W_out  = (const float*)d_in[6];
  const float* b_out  = (const float*)d_in[7];
  const float* g_out  = (const float*)d_in[8];
  const float* be_out = (const float*)d_in[9];
  const float* m_out  = (const float*)d_in[10];
  const float* v_out  = (const float*)d_in[11];
  const float* W_ff   = (const float*)d_in[12];
  const float* b_ff   = (const float*)d_in[13];
  const float* g_ff   = (const float*)d_in[14];
  const float* be_ff  = (const float*)d_in[15];
  const float* m_ff   = (const float*)d_in[16];
  const float* v_ff   = (const float*)d_in[17];
  const float* W_t    = (const float*)d_in[18];
  const float* b_t    = (const float*)d_in[19];
  const float* g_t    = (const float*)d_in[20];
  const float* be_t   = (const float*)d_in[21];
  const float* m_t    = (const float*)d_in[22];
  const float* v_t    = (const float*)d_in[23];

  float* att_raw = (float*)d_ws;                         // [0, 186624)
  u16* attT = (u16*)((char*)d_ws + 262144);              // 131072 B
  u16* y4w = (u16*)((char*)d_ws + 524288);               // 44236800 B + pad
  const size_t NEED = 524288 + 44236800 + 1024;

  if (ws_size >= NEED) {
    hipMemsetAsync(d_ws, 0, 524288, stream);  // att_raw + attT pads
    k_att<<<dim3(50, 32), 256, 0, stream>>>(x, pe, W_in, b_in, att_raw);
    k_att_fin<<<dim3(183), 256, 0, stream>>>(att_raw, alphas, att0, attT);
    k_mid<<<dim3(50, 32), 256, 0, stream>>>(
        x, attT, W_out, b_out, g_out, be_out, m_out, v_out,
        W_ff, b_ff, g_ff, be_ff, m_ff, v_ff, y4w);
    k_conv<<<dim3(50, 32), 256, 0, stream>>>(y4w, W_t, b_t, g_t, be_t, m_t, v_t,
                                             (float*)d_out);
  } else {
    hipMemsetAsync(att_raw, 0, 32 * 2 * 729 * sizeof(float), stream);
    k_att<<<dim3(50, 32), 256, 0, stream>>>(x, pe, W_in, b_in, att_raw);
    k_att_fin<<<dim3(183), 256, 0, stream>>>(att_raw, alphas, att0, (u16*)nullptr);
    k_fused_fb<<<dim3(50, 32), 256, 0, stream>>>(
        x, att_raw, W_out, b_out, g_out, be_out, m_out, v_out,
        W_ff, b_ff, g_ff, be_ff, m_ff, v_ff,
        W_t, b_t, g_t, be_t, m_t, v_t, (float*)d_out);
  }
}

// Round 7
// 450.152 us; speedup vs baseline: 1.1017x; 1.0848x over previous
//
#include <hip/hip_runtime.h>
#include <hip/hip_bf16.h>

typedef __hip_bfloat16 bf16;
typedef unsigned short u16;
typedef __attribute__((ext_vector_type(4))) short short4_t;
typedef __attribute__((ext_vector_type(8))) short short8;
typedef __attribute__((ext_vector_type(4))) float f32x4;

#define LEAK 0.1f
#define EPS_ 1e-5f
#define MFMA(a, b, c) __builtin_amdgcn_mfma_f32_16x16x32_bf16(a, b, c, 0, 0, 0)
// N=32 C=64 T=400 V=27 S=2 IC=16 O=64 -- fp32 I/O, bf16 MFMA internally

__device__ __forceinline__ float u2f(u16 u) { return __uint_as_float(((unsigned int)u) << 16); }
__device__ __forceinline__ u16 f2u(float f) {
  bf16 h = __float2bfloat16(f);
  u16 r;
  __builtin_memcpy(&r, &h, 2);
  return r;
}
__device__ __forceinline__ f32x4 z4() { f32x4 z = {0.f, 0.f, 0.f, 0.f}; return z; }
__device__ __forceinline__ short8 z8() { short8 z = {0, 0, 0, 0, 0, 0, 0, 0}; return z; }

// ---------------------------------------------------------------------------
// K_att: logits. Block=(n, 16 t) in TWO 8-slice rounds (halves blocks+atomics
// vs R6). Per round: coalesced stage of (x+pe)^T -> barrier -> wave-private
// slices {w, w+4}: qk GEMM, pack qk^T over staging rows, logit MFMAs in regs.
// Block-reduce, 1458 atomics/block. LDS 37 KB.
// ---------------------------------------------------------------------------
__global__ __launch_bounds__(256, 4) void k_att(
    const float* __restrict__ x, const float* __restrict__ pe,
    const float* __restrict__ W_in, const float* __restrict__ b_in,
    float* __restrict__ att_raw)
{
  __shared__ u16 syT[8][32][72];  // per-slice [v][c] (x+pe)^T; later qk^T [v][r]
  __shared__ float sb[64];
  const int tid = threadIdx.x, w = tid >> 6, lane = tid & 63;
  const int m = lane & 15, quad = lane >> 4;
  const int n = blockIdx.y, t0 = blockIdx.x * 16;
  const long xb = (long)n * 691200 + t0 * 27;

  for (int i = tid; i < 8 * 5 * 72; i += 256) {  // zero pad rows 27..31
    int sl = i / 360, r = i % 360;
    syT[sl][27 + r / 72][r % 72] = 0;
  }
  short8 aWin[4][2];
#pragma unroll
  for (int mt = 0; mt < 4; ++mt)
#pragma unroll
    for (int kf = 0; kf < 2; ++kf) {
      short8 tt;
#pragma unroll
      for (int j = 0; j < 8; ++j)
        tt[j] = (short)f2u(W_in[(16 * mt + m) * 64 + 32 * kf + 8 * quad + j]);
      aWin[mt][kf] = tt;
    }
  if (tid < 64) sb[tid] = b_in[tid];

  f32x4 accL[2][2][2];
#pragma unroll
  for (int s = 0; s < 2; ++s)
#pragma unroll
    for (int a = 0; a < 2; ++a)
#pragma unroll
      for (int b = 0; b < 2; ++b) accL[s][a][b] = z4();

  for (int rd = 0; rd < 2; ++rd) {
    if (rd) __syncthreads();  // protect restage vs prev round's reads
    const int fb = t0 * 27 + rd * 216;
    for (int i = tid; i < 64 * 216; i += 256) {  // coalesced staging
      int c = i / 216, f = i % 216;
      syT[f / 27][f % 27][c] =
          f2u(x[(long)n * 691200 + (long)c * 10800 + fb + f] + pe[c * 10800 + fb + f]);
    }
    __syncthreads();

#pragma unroll
    for (int ss = 0; ss < 2; ++ss) {
      const int sl = w + 4 * ss;
      short8 bfr[2][2];
#pragma unroll
      for (int nt = 0; nt < 2; ++nt)
#pragma unroll
        for (int kf = 0; kf < 2; ++kf)
          bfr[nt][kf] = *(const short8*)&syT[sl][16 * nt + m][32 * kf + 8 * quad];
      f32x4 q[4][2];
#pragma unroll
      for (int mt = 0; mt < 4; ++mt)
#pragma unroll
        for (int nt = 0; nt < 2; ++nt) {
          q[mt][nt] = MFMA(aWin[mt][0], bfr[nt][0], z4());
          q[mt][nt] = MFMA(aWin[mt][1], bfr[nt][1], q[mt][nt]);
        }
#pragma unroll
      for (int nt = 0; nt < 2; ++nt) {
        int v = 16 * nt + m;
        if (v < 27) {
#pragma unroll
          for (int mt = 0; mt < 4; ++mt) {
            short4_t pk;
#pragma unroll
            for (int reg = 0; reg < 4; ++reg)
              pk[reg] = (short)f2u(q[mt][nt][reg] + sb[16 * mt + 4 * quad + reg]);
            *(short4_t*)&syT[sl][v][16 * mt + 4 * quad] = pk;
          }
        }
      }
      __asm__ volatile("s_waitcnt lgkmcnt(0)" ::: "memory");
#pragma unroll
      for (int s = 0; s < 2; ++s) {
        short8 aq[2], bk[2];
#pragma unroll
        for (int ua = 0; ua < 2; ++ua)
          aq[ua] = (quad < 2) ? *(const short8*)&syT[sl][16 * ua + m][16 * s + 8 * quad] : z8();
#pragma unroll
        for (int nt = 0; nt < 2; ++nt)
          bk[nt] = (quad < 2) ? *(const short8*)&syT[sl][16 * nt + m][32 + 16 * s + 8 * quad] : z8();
#pragma unroll
        for (int ua = 0; ua < 2; ++ua)
#pragma unroll
          for (int nt = 0; nt < 2; ++nt) accL[s][ua][nt] = MFMA(aq[ua], bk[nt], accL[s][ua][nt]);
      }
    }
  }

  float* fred = (float*)&syT[0][0][0];  // [8][27][28]
  __syncthreads();
#pragma unroll
  for (int s = 0; s < 2; ++s)
#pragma unroll
    for (int ua = 0; ua < 2; ++ua)
#pragma unroll
      for (int nt = 0; nt < 2; ++nt)
#pragma unroll
        for (int reg = 0; reg < 4; ++reg) {
          int u = 16 * ua + 4 * quad + reg, v = 16 * nt + m;
          if (u < 27 && v < 27) fred[((w * 2 + s) * 27 + u) * 28 + v] = accL[s][ua][nt][reg];
        }
  __syncthreads();
  for (int i = tid; i < 1458; i += 256) {
    int s = i / 729, r = i % 729, u = r / 27, v = r % 27;
    float sum = fred[((0 + s) * 27 + u) * 28 + v] + fred[((2 + s) * 27 + u) * 28 + v] +
                fred[((4 + s) * 27 + u) * 28 + v] + fred[((6 + s) * 27 + u) * 28 + v];
    atomicAdd(&att_raw[(n * 2 + s) * 729 + r], sum);
  }
}

// ---------------------------------------------------------------------------
// K_fin: finalize att in-place (fp32) and optionally write transposed bf16
// attT[n][s][v(32)][u(32)] for K_mid's B-frags (pads pre-zeroed by memset).
// ---------------------------------------------------------------------------
__global__ __launch_bounds__(256) void k_att_fin(
    float* __restrict__ att, const float* __restrict__ alphas,
    const float* __restrict__ att0, u16* __restrict__ attT)
{
  int i = blockIdx.x * 256 + threadIdx.x;
  if (i >= 32 * 2 * 729) return;
  int ns = i / 729, s = ns & 1, r = i % 729, u = r / 27, v = r % 27;
  float fin = tanhf(att[i] * (1.f / 6400.f)) * alphas[s] + att0[s * 729 + r];
  att[i] = fin;
  if (attT) attT[(ns * 32 + v) * 32 + u] = f2u(fin);
}

// ---------------------------------------------------------------------------
// K_mid: y2 -> y3 -> y4(ws, bf16 [n][t][v][c]). Block=(n, 8 t), 4 phases of 2
// slices. Per phase: coalesced stage of x pair tile into LDS; A-frags AND both
// residual reads served from LDS (x global-read once total). 4 barriers/phase.
// LDS 36.9 KB -> 4 blocks/CU.
// ---------------------------------------------------------------------------
__global__ __launch_bounds__(256, 4) void k_mid(
    const float* __restrict__ x, const u16* __restrict__ attT,
    const float* __restrict__ W_out, const float* __restrict__ b_out,
    const float* __restrict__ g_out, const float* __restrict__ be_out,
    const float* __restrict__ m_out, const float* __restrict__ v_out,
    const float* __restrict__ W_ff, const float* __restrict__ b_ff,
    const float* __restrict__ g_ff, const float* __restrict__ be_ff,
    const float* __restrict__ m_ff, const float* __restrict__ v_ff,
    u16* __restrict__ y4w)
{
  __shared__ u16 sx[64][72];       // [c][sp*32+u], u pads 27..31 zero
  __shared__ u16 sy2[2][32][136];  // [sp][v][s*64+c]
  __shared__ u16 sy3[2][32][72];   // [sp][v][c]
  __shared__ float sBN[4][64];
  const int tid = threadIdx.x, w = tid >> 6, lane = tid & 63;
  const int m = lane & 15, quad = lane >> 4;
  const int mh = w & 1, sp = w >> 1;
  const int n = blockIdx.y, t0 = blockIdx.x * 8;
  const long xb = (long)n * 691200;

  for (int i = tid; i < 64 * 10; i += 256) {  // sx u-pads
    int c = i / 10, j = i % 10;
    sx[c][(j < 5) ? (27 + j) : (54 + j)] = 0;
  }
  for (int i = tid; i < 2 * 5 * 136; i += 256) {
    int p = i / 680, r = i % 680;
    sy2[p][27 + r / 136][r % 136] = 0;
  }
  for (int i = tid; i < 2 * 5 * 72; i += 256) {
    int p = i / 360, r = i % 360;
    sy3[p][27 + r / 72][r % 72] = 0;
  }
  if (tid < 64) {
    int o = tid;
    float sc;
    sc = g_out[o] * rsqrtf(v_out[o] + EPS_); sBN[0][o] = sc; sBN[1][o] = (b_out[o] - m_out[o]) * sc + be_out[o];
    sc = g_ff[o] * rsqrtf(v_ff[o] + EPS_);   sBN[2][o] = sc; sBN[3][o] = (b_ff[o] - m_ff[o]) * sc + be_ff[o];
  }
  short8 aWo[2][4], aWf[2][2];
#pragma unroll
  for (int ct = 0; ct < 2; ++ct) {
#pragma unroll
    for (int kf = 0; kf < 4; ++kf) {
      short8 tt;
#pragma unroll
      for (int j = 0; j < 8; ++j)
        tt[j] = (short)f2u(W_out[(32 * mh + 16 * ct + m) * 128 + 32 * kf + 8 * quad + j]);
      aWo[ct][kf] = tt;
    }
#pragma unroll
    for (int kf = 0; kf < 2; ++kf) {
      short8 tt;
#pragma unroll
      for (int j = 0; j < 8; ++j)
        tt[j] = (short)f2u(W_ff[(32 * mh + 16 * ct + m) * 64 + 32 * kf + 8 * quad + j]);
      aWf[ct][kf] = tt;
    }
  }
  __syncthreads();

  for (int g = 0; g < 4; ++g) {
    const int tp2 = t0 + 2 * g;
    // stage x pair: coalesced 216-B runs per c
    for (int i = tid; i < 3456; i += 256) {
      int c = i / 54, f = i % 54, sp2 = f / 27, u = f % 27;
      sx[c][sp2 * 32 + u] = f2u(x[xb + (long)c * 10800 + tp2 * 27 + f]);
    }
    __syncthreads();
    const int t = tp2 + sp;
    // S2: y2 = x . att (A from sx, B from attT in L2)
    short8 ax[2];
#pragma unroll
    for (int ct = 0; ct < 2; ++ct)
      ax[ct] = *(const short8*)&sx[32 * mh + 16 * ct + m][sp * 32 + 8 * quad];
#pragma unroll
    for (int s = 0; s < 2; ++s) {
      short8 batt[2];
#pragma unroll
      for (int nt = 0; nt < 2; ++nt)
        batt[nt] = *(const short8*)&attT[((n * 2 + s) * 32 + 16 * nt + m) * 32 + 8 * quad];
      f32x4 a2[2][2];
#pragma unroll
      for (int ct = 0; ct < 2; ++ct)
#pragma unroll
        for (int nt = 0; nt < 2; ++nt) a2[ct][nt] = MFMA(ax[ct], batt[nt], z4());
#pragma unroll
      for (int ct = 0; ct < 2; ++ct)
#pragma unroll
        for (int nt = 0; nt < 2; ++nt) {
          int v = 16 * nt + m;
          if (v < 27) {
            short4_t pk;
#pragma unroll
            for (int reg = 0; reg < 4; ++reg) pk[reg] = (short)f2u(a2[ct][nt][reg]);
            *(short4_t*)&sy2[sp][v][64 * s + 32 * mh + 16 * ct + 4 * quad] = pk;
          }
        }
    }
    __syncthreads();
    // S3: y3 = lrelu(x + bn(W_out @ y2)), K=128; residual from sx
    {
      f32x4 a3[2][2];
#pragma unroll
      for (int ct = 0; ct < 2; ++ct)
#pragma unroll
        for (int nt = 0; nt < 2; ++nt) a3[ct][nt] = z4();
#pragma unroll
      for (int kf = 0; kf < 4; ++kf)
#pragma unroll
        for (int nt = 0; nt < 2; ++nt) {
          short8 b = *(const short8*)&sy2[sp][16 * nt + m][32 * kf + 8 * quad];
#pragma unroll
          for (int ct = 0; ct < 2; ++ct) a3[ct][nt] = MFMA(aWo[ct][kf], b, a3[ct][nt]);
        }
#pragma unroll
      for (int ct = 0; ct < 2; ++ct)
#pragma unroll
        for (int nt = 0; nt < 2; ++nt) {
          int v = 16 * nt + m;
          if (v < 27) {
            short4_t pk;
#pragma unroll
            for (int reg = 0; reg < 4; ++reg) {
              int o = 32 * mh + 16 * ct + 4 * quad + reg;
              float r = u2f(sx[o][sp * 32 + v]) + a3[ct][nt][reg] * sBN[0][o] + sBN[1][o];
              pk[reg] = (short)f2u((r >= 0.f) ? r : LEAK * r);
            }
            *(short4_t*)&sy3[sp][v][32 * mh + 16 * ct + 4 * quad] = pk;
          }
        }
    }
    __syncthreads();
    // S4: y4 = lrelu(x + bn(W_ff @ y3)) -> ws bf16 [n][t][v][c]
    {
      f32x4 a4[2][2];
#pragma unroll
      for (int ct = 0; ct < 2; ++ct)
#pragma unroll
        for (int nt = 0; nt < 2; ++nt) a4[ct][nt] = z4();
#pragma unroll
      for (int kf = 0; kf < 2; ++kf)
#pragma unroll
        for (int nt = 0; nt < 2; ++nt) {
          short8 b = *(const short8*)&sy3[sp][16 * nt + m][32 * kf + 8 * quad];
#pragma unroll
          for (int ct = 0; ct < 2; ++ct) a4[ct][nt] = MFMA(aWf[ct][kf], b, a4[ct][nt]);
        }
#pragma unroll
      for (int ct = 0; ct < 2; ++ct)
#pragma unroll
        for (int nt = 0; nt < 2; ++nt) {
          int v = 16 * nt + m;
          if (v < 27) {
            short4_t pk;
#pragma unroll
            for (int reg = 0; reg < 4; ++reg) {
              int o = 32 * mh + 16 * ct + 4 * quad + reg;
              float r = u2f(sx[o][sp * 32 + v]) + a4[ct][nt][reg] * sBN[2][o] + sBN[3][o];
              pk[reg] = (short)f2u((r >= 0.f) ? r : LEAK * r);
            }
            *(short4_t*)&y4w[((long)(n * 400 + t) * 27 + v) * 64 + 32 * mh + 16 * ct + 4 * quad] = pk;
          }
        }
    }
    __syncthreads();  // protect sx restage next phase
  }
}

// ---------------------------------------------------------------------------
// K_conv: z = lrelu(y4 + bn(conv3 @ y4)). Block=(n, 8 t) in two 4-slice
// halves. Wave (mh, sh) computes slices {sh, sh+2} of the half into LDS
// sz[4][64][28] fp32; then a cooperative flat loop writes 432-B-per-o-row
// contiguous, fully coalesced output. 3 barriers, LDS 28.7 KB.
// ---------------------------------------------------------------------------
__global__ __launch_bounds__(256, 4) void k_conv(
    const u16* __restrict__ y4w, const float* __restrict__ W_t,
    const float* __restrict__ b_t, const float* __restrict__ g_t,
    const float* __restrict__ be_t, const float* __restrict__ m_t,
    const float* __restrict__ v_t, float* __restrict__ out)
{
  __shared__ float sz[4][64][28];
  const int tid = threadIdx.x, w = tid >> 6, lane = tid & 63;
  const int m = lane & 15, quad = lane >> 4;
  const int mh = w & 1, sh = w >> 1;
  const int n = blockIdx.y, t0 = blockIdx.x * 8;

  short8 aWt[2][6];  // kf = 2*dt + ih
#pragma unroll
  for (int ct = 0; ct < 2; ++ct)
#pragma unroll
    for (int kf = 0; kf < 6; ++kf) {
      int dt = kf >> 1, ih = kf & 1;
      short8 tt;
#pragma unroll
      for (int j = 0; j < 8; ++j)
        tt[j] = (short)f2u(W_t[((32 * mh + 16 * ct + m) * 64 + 32 * ih + 8 * quad + j) * 3 + dt]);
      aWt[ct][kf] = tt;
    }
  float At[2][4], Bt[2][4];
#pragma unroll
  for (int ct = 0; ct < 2; ++ct)
#pragma unroll
    for (int reg = 0; reg < 4; ++reg) {
      int o = 32 * mh + 16 * ct + 4 * quad + reg;
      float sc = g_t[o] * rsqrtf(v_t[o] + EPS_);
      At[ct][reg] = sc;
      Bt[ct][reg] = (b_t[o] - m_t[o]) * sc + be_t[o];
    }

  for (int h = 0; h < 2; ++h) {
    const int ta = t0 + 4 * h;
    if (h) __syncthreads();  // protect sz restage vs prev coop-write reads
#pragma unroll
    for (int ss = 0; ss < 2; ++ss) {
      const int tq = sh + 2 * ss, t = ta + tq;
      f32x4 ac[2][2];
#pragma unroll
      for (int ct = 0; ct < 2; ++ct)
#pragma unroll
        for (int nt = 0; nt < 2; ++nt) ac[ct][nt] = z4();
#pragma unroll
      for (int dt = 0; dt < 3; ++dt) {
        int tp = t - 1 + dt;
        bool ok = (tp >= 0) && (tp < 400);
#pragma unroll
        for (int ih = 0; ih < 2; ++ih)
#pragma unroll
          for (int nt = 0; nt < 2; ++nt) {
            short8 b = ok ? *(const short8*)&y4w[((long)(n * 400 + tp) * 27 + 16 * nt + m) * 64 +
                                                 32 * ih + 8 * quad]
                          : z8();
#pragma unroll
            for (int ct = 0; ct < 2; ++ct) ac[ct][nt] = MFMA(aWt[ct][2 * dt + ih], b, ac[ct][nt]);
          }
      }
#pragma unroll
      for (int ct = 0; ct < 2; ++ct)
#pragma unroll
        for (int nt = 0; nt < 2; ++nt) {
          int v = 16 * nt + m;
          if (v < 27) {
            short4_t ry = *(const short4_t*)&y4w[((long)(n * 400 + t) * 27 + v) * 64 +
                                                 32 * mh + 16 * ct + 4 * quad];
#pragma unroll
            for (int reg = 0; reg < 4; ++reg) {
              float r = u2f(ry[reg]) + ac[ct][nt][reg] * At[ct][reg] + Bt[ct][reg];
              sz[tq][32 * mh + 16 * ct + 4 * quad + reg][v] = (r >= 0.f) ? r : LEAK * r;
            }
          }
        }
    }
    __syncthreads();
    // cooperative coalesced write: per o, 108 contiguous dwords (4t x 27v)
    const long ob = (long)n * 691200 + ta * 27;
    for (int j = tid; j < 6912; j += 256) {
      int o = j / 108, r = j % 108;
      out[ob + (long)o * 10800 + r] = sz[r / 27][o][r % 27];
    }
  }
}

// ---------------------------------------------------------------------------
// Fallback (ws too small): R4's verified fused kernel, reads finalized att.
// ---------------------------------------------------------------------------
__global__ __launch_bounds__(256) void k_fused_fb(
    const float* __restrict__ x, const float* __restrict__ att,
    const float* __restrict__ W_out, const float* __restrict__ b_out,
    const float* __restrict__ g_out, const float* __restrict__ be_out,
    const float* __restrict__ m_out, const float* __restrict__ v_out,
    const float* __restrict__ W_ff, const float* __restrict__ b_ff,
    const float* __restrict__ g_ff, const float* __restrict__ be_ff,
    const float* __restrict__ m_ff, const float* __restrict__ v_ff,
    const float* __restrict__ W_t, const float* __restrict__ b_t,
    const float* __restrict__ g_t, const float* __restrict__ be_t,
    const float* __restrict__ m_t, const float* __restrict__ v_t,
    float* __restrict__ out)
{
  __shared__ u16 sx[64][40];
  __shared__ u16 sy2[32][136];
  __shared__ u16 sy3[32][72];
  __shared__ u16 sy4[3][32][72];
  const int tid = threadIdx.x;
  const int w = tid >> 6, lane = tid & 63;
  const int m = lane & 15, quad = lane >> 4;
  const int n = blockIdx.y, t0 = blockIdx.x * 8;

  for (int i = tid; i < 64 * 40; i += 256) sx[0][i] = 0;
  for (int i = tid; i < 32 * 136; i += 256) sy2[0][i] = 0;
  for (int i = tid; i < 32 * 72; i += 256) sy3[0][i] = 0;
  for (int i = tid; i < 3 * 32 * 72; i += 256) sy4[0][0][i] = 0;

  short8 aWo[4], aWf[2], aWt[6], bAtt[4];
#pragma unroll
  for (int kf = 0; kf < 4; ++kf) {
    short8 tt;
#pragma unroll
    for (int j = 0; j < 8; ++j)
      tt[j] = (short)f2u(W_out[(16 * w + m) * 128 + 32 * kf + 8 * quad + j]);
    aWo[kf] = tt;
  }
#pragma unroll
  for (int kf = 0; kf < 2; ++kf) {
    short8 tt;
#pragma unroll
    for (int j = 0; j < 8; ++j)
      tt[j] = (short)f2u(W_ff[(16 * w + m) * 64 + 32 * kf + 8 * quad + j]);
    aWf[kf] = tt;
  }
#pragma unroll
  for (int kf = 0; kf < 6; ++kf) {
    short8 tt;
    int dt = kf >> 1;
#pragma unroll
    for (int j = 0; j < 8; ++j) {
      int ii = 32 * (kf & 1) + 8 * quad + j;
      tt[j] = (short)f2u(W_t[((16 * w + m) * 64 + ii) * 3 + dt]);
    }
    aWt[kf] = tt;
  }
#pragma unroll
  for (int s = 0; s < 2; ++s)
#pragma unroll
    for (int nt = 0; nt < 2; ++nt) {
      short8 tt;
#pragma unroll
      for (int j = 0; j < 8; ++j) {
        int u = 8 * quad + j, v = 16 * nt + m;
        int idx = (n * 2 + s) * 729 + ((u < 27) ? u : 0) * 27 + ((v < 27) ? v : 0);
        tt[j] = (u < 27 && v < 27) ? (short)f2u(att[idx]) : (short)0;
      }
      bAtt[s * 2 + nt] = tt;
    }
  float Ao[4], Bo[4], Af[4], Bf[4], At[4], Bt[4];
#pragma unroll
  for (int reg = 0; reg < 4; ++reg) {
    int o = 16 * w + quad * 4 + reg;
    float sc;
    sc = g_out[o] * rsqrtf(v_out[o] + EPS_); Ao[reg] = sc; Bo[reg] = (b_out[o] - m_out[o]) * sc + be_out[o];
    sc = g_ff[o] * rsqrtf(v_ff[o] + EPS_);   Af[reg] = sc; Bf[reg] = (b_ff[o] - m_ff[o]) * sc + be_ff[o];
    sc = g_t[o] * rsqrtf(v_t[o] + EPS_);     At[reg] = sc; Bt[reg] = (b_t[o] - m_t[o]) * sc + be_t[o];
  }
  __syncthreads();

  for (int st = 0; st < 10; ++st) {
    const int t = t0 - 1 + st;
    const bool valid = (t >= 0) && (t < 400);
    if (valid) {
      for (int i = tid; i < 1728; i += 256) {
        int c = i / 27, u = i % 27;
        sx[c][u] = f2u(x[((n * 64 + c) * 400 + t) * 27 + u]);
      }
    }
    __syncthreads();
    if (valid) {
      short8 ax = *(const short8*)&sx[16 * w + m][8 * quad];
      f32x4 acc[4];
#pragma unroll
      for (int f = 0; f < 4; ++f) acc[f] = MFMA(ax, bAtt[f], z4());
#pragma unroll
      for (int s = 0; s < 2; ++s)
#pragma unroll
        for (int nt = 0; nt < 2; ++nt) {
          int v = 16 * nt + m;
          if (v < 27) {
            f32x4 a = acc[s * 2 + nt];
#pragma unroll
            for (int reg = 0; reg < 4; ++reg)
              sy2[v][s * 64 + 16 * w + quad * 4 + reg] = f2u(a[reg]);
          }
        }
    }
    __syncthreads();
    if (valid) {
      f32x4 a0 = z4(), a1 = z4();
#pragma unroll
      for (int kf = 0; kf < 4; ++kf) {
        short8 b0 = *(const short8*)&sy2[m][32 * kf + 8 * quad];
        short8 b1 = *(const short8*)&sy2[16 + m][32 * kf + 8 * quad];
        a0 = MFMA(aWo[kf], b0, a0);
        a1 = MFMA(aWo[kf], b1, a1);
      }
#pragma unroll
      for (int nt = 0; nt < 2; ++nt) {
        f32x4 a = nt ? a1 : a0;
        int v = 16 * nt + m;
        if (v < 27) {
#pragma unroll
          for (int reg = 0; reg < 4; ++reg) {
            int o = 16 * w + quad * 4 + reg;
            float r = u2f(sx[o][v]) + a[reg] * Ao[reg] + Bo[reg];
            sy3[v][o] = f2u((r >= 0.f) ? r : LEAK * r);
          }
        }
      }
    }
    __syncthreads();
    if (valid) {
      f32x4 a0 = z4(), a1 = z4();
#pragma unroll
      for (int kf = 0; kf < 2; ++kf) {
        short8 b0 = *(const short8*)&sy3[m][32 * kf + 8 * quad];
        short8 b1 = *(const short8*)&sy3[16 + m][32 * kf + 8 * quad];
        a0 = MFMA(aWf[kf], b0, a0);
        a1 = MFMA(aWf[kf], b1, a1);
      }
#pragma unroll
      for (int nt = 0; nt < 2; ++nt) {
        f32x4 a = nt ? a1 : a0;
        int v = 16 * nt + m;
        if (v < 27) {
#pragma unroll
          for (int reg = 0; reg < 4; ++reg) {
            int o = 16 * w + quad * 4 + reg;
            float r = u2f(sx[o][v]) + a[reg] * Af[reg] + Bf[reg];
            sy4[st % 3][v][o] = f2u((r >= 0.f) ? r : LEAK * r);
          }
        }
      }
    } else {
      for (int i = tid; i < 27 * 64; i += 256)
        sy4[st % 3][i / 64][i % 64] = 0;
    }
    __syncthreads();
    if (st >= 2) {
      f32x4 a0 = z4(), a1 = z4();
#pragma unroll
      for (int kf = 0; kf < 6; ++kf) {
        int sl = (st - 2 + (kf >> 1)) % 3;
        int col = 32 * (kf & 1) + 8 * quad;
        short8 b0 = *(const short8*)&sy4[sl][m][col];
        short8 b1 = *(const short8*)&sy4[sl][16 + m][col];
        a0 = MFMA(aWt[kf], b0, a0);
        a1 = MFMA(aWt[kf], b1, a1);
      }
      int t_out = t0 + st - 2;
#pragma unroll
      for (int nt = 0; nt < 2; ++nt) {
        f32x4 a = nt ? a1 : a0;
        int v = 16 * nt + m;
        if (v < 27) {
#pragma unroll
          for (int reg = 0; reg < 4; ++reg) {
            int o = 16 * w + quad * 4 + reg;
            float r = u2f(sy4[(st - 1) % 3][v][o]) + a[reg] * At[reg] + Bt[reg];
            out[((n * 64 + o) * 400 + t_out) * 27 + v] = (r >= 0.f) ? r : LEAK * r;
          }
        }
      }
    }
  }
}

// ---------------------------------------------------------------------------
extern "C" void kernel_launch(void* const* d_in, const int* in_sizes, int n_in,
                              void* d_out, int out_size, void* d_ws, size_t ws_size,
                              hipStream_t stream)
{
  const float* x      = (const float*)d_in[0];
  const float* pe     = (const float*)d_in[1];
  const float* W_in   = (const float*)d_in[2];
  const float* b_in   = (const float*)d_in[3];
  const float* alphas = (const float*)d_in[4];
  const float* att0   = (const float*)d_in[5];
  const float* W_out  = (const float*)d_in[6];
  const float* b_out  = (const float*)d_in[7];
  const float* g_out  = (const float*)d_in[8];
  const float* be_out = (const float*)d_in[9];
  const float* m_out  = (const float*)d_in[10];
  const float* v_out  = (const float*)d_in[11];
  const float* W_ff   = (const float*)d_in[12];
  const float* b_ff   = (const float*)d_in[13];
  const float* g_ff   = (const float*)d_in[14];
  const float* be_ff  = (const float*)d_in[15];
  const float* m_ff   = (const float*)d_in[16];
  const float* v_ff   = (const float*)d_in[17];
  const float* W_t    = (const float*)d_in[18];
  const float* b_t    = (const float*)d_in[19];
  const float* g_t    = (const float*)d_in[20];
  const float* be_t   = (const float*)d_in[21];
  const float* m_t    = (const float*)d_in[22];
  const float* v_t    = (const float*)d_in[23];

  float* att_raw = (float*)d_ws;                         // [0, 186624)
  u16* attT = (u16*)((char*)d_ws + 262144);              // 131072 B
  u16* y4w = (u16*)((char*)d_ws + 524288);               // 44236800 B + pad
  const size_t NEED = 524288 + 44236800 + 1024;

  if (ws_size >= NEED) {
    hipMemsetAsync(d_ws, 0, 524288, stream);  // att_raw + attT pads
    k_att<<<dim3(25, 32), 256, 0, stream>>>(x, pe, W_in, b_in, att_raw);
    k_att_fin<<<dim3(183), 256, 0, stream>>>(att_raw, alphas, att0, attT);
    k_mid<<<dim3(50, 32), 256, 0, stream>>>(
        x, attT, W_out, b_out, g_out, be_out, m_out, v_out,
        W_ff, b_ff, g_ff, be_ff, m_ff, v_ff, y4w);
    k_conv<<<dim3(50, 32), 256, 0, stream>>>(y4w, W_t, b_t, g_t, be_t, m_t, v_t,
                                             (float*)d_out);
  } else {
    hipMemsetAsync(att_raw, 0, 32 * 2 * 729 * sizeof(float), stream);
    k_att<<<dim3(25, 32), 256, 0, stream>>>(x, pe, W_in, b_in, att_raw);
    k_att_fin<<<dim3(183), 256, 0, stream>>>(att_raw, alphas, att0, (u16*)nullptr);
    k_fused_fb<<<dim3(50, 32), 256, 0, stream>>>(
        x, att_raw, W_out, b_out, g_out, be_out, m_out, v_out,
        W_ff, b_ff, g_ff, be_ff, m_ff, v_ff,
        W_t, b_t, g_t, be_t, m_t, v_t, (float*)d_out);
  }
}